// Round 1
// baseline (1840.370 us; speedup 1.0000x reference)
//
#include <hip/hip_runtime.h>

#define G 8192
#define IMG_W 512
#define IMG_H 512
#define SORT_THREADS 1024
#define CH 256
#define ALPHA_THRESH (1.0f/255.0f)
#define ALPHA_CAP 0.99f
#define TRANS_THRESH 1e-4f
// exp(-5.55) = 0.003887 < 1/255 = 0.003922, and op < 1, so sigma >= 5.55
// can NEVER pass the alpha threshold -> conservative fast skip.
#define SIGMA_SKIP 5.55f

// -----------------------------------------------------------------------
// Kernel 1: stable depth sort. Single block, bitonic sort of 64-bit keys
// (float_bits(depth) << 32) | index. Depths are all positive so float bit
// pattern is monotonic as uint32; index in low bits reproduces argsort
// stability exactly. Writes permutation into ws (G ints = 32 KB).
// -----------------------------------------------------------------------
__global__ __launch_bounds__(SORT_THREADS)
void sort_kernel(const float* __restrict__ depths, int* __restrict__ order)
{
    __shared__ unsigned long long keys[G];   // 64 KB LDS
    const int t = threadIdx.x;
    for (int i = t; i < G; i += SORT_THREADS) {
        unsigned int fb = __float_as_uint(depths[i]);
        keys[i] = ((unsigned long long)fb << 32) | (unsigned int)i;
    }
    __syncthreads();
    for (int k = 2; k <= G; k <<= 1) {
        for (int j = k >> 1; j > 0; j >>= 1) {
            for (int i = t; i < G; i += SORT_THREADS) {
                int ixj = i ^ j;
                if (ixj > i) {
                    unsigned long long va = keys[i], vb = keys[ixj];
                    bool up = ((i & k) == 0);
                    if ((va > vb) == up) { keys[i] = vb; keys[ixj] = va; }
                }
            }
            __syncthreads();
        }
    }
    for (int i = t; i < G; i += SORT_THREADS)
        order[i] = (int)(keys[i] & 0xffffffffu);
}

// -----------------------------------------------------------------------
// Kernel 2: rasterize. One thread per pixel, 16x16 tile per block.
// Gaussians staged into LDS in depth-order chunks of 256 (indirect gather
// through the permutation; source arrays total 288 KB -> L2-resident).
// Exact early termination: once T < 1e-4 all later weights are masked to 0
// by the reference, so the per-pixel scan can stop; block exits when all
// 256 pixels are done (__syncthreads_and).
// -----------------------------------------------------------------------
__global__ __launch_bounds__(256)
void raster_kernel(const int*   __restrict__ order,
                   const float* __restrict__ means2d,   // (G,2)
                   const float* __restrict__ conics,    // (G,3)
                   const float* __restrict__ colors,    // (G,3)
                   const float* __restrict__ opac,      // (G,)
                   float*       __restrict__ out)       // (H,W,3)
{
    __shared__ float smx[CH], smy[CH], sa[CH], sb[CH], sc[CH];
    __shared__ float sr[CH], sg[CH], sbl[CH], sop[CH];

    const int tx = threadIdx.x, ty = threadIdx.y;
    const int x = blockIdx.x * 16 + tx;
    const int y = blockIdx.y * 16 + ty;
    const float px = (float)x + 0.5f;
    const float py = (float)y + 0.5f;
    const int t = ty * 16 + tx;

    float T = 1.0f;
    float accr = 0.0f, accg = 0.0f, accb = 0.0f;
    bool done = false;

    for (int base = 0; base < G; base += CH) {
        // cooperative chunk stage (each thread loads one gaussian's params)
        int idx = order[base + t];
        smx[t] = means2d[2 * idx];
        smy[t] = means2d[2 * idx + 1];
        sa [t] = conics[3 * idx];
        sb [t] = conics[3 * idx + 1];
        sc [t] = conics[3 * idx + 2];
        sr [t] = colors[3 * idx];
        sg [t] = colors[3 * idx + 1];
        sbl[t] = colors[3 * idx + 2];
        sop[t] = opac[idx];
        __syncthreads();

        if (!done) {
            for (int i = 0; i < CH; ++i) {
                float dx = px - smx[i];
                float dy = py - smy[i];
                float sigma = 0.5f * (sa[i] * dx * dx + sc[i] * dy * dy)
                            + sb[i] * dx * dy;
                // sigma < 0 -> masked; sigma >= SIGMA_SKIP -> alpha provably
                // below 1/255 (op < 1). Skip the exp on both.
                if (sigma >= 0.0f && sigma < SIGMA_SKIP) {
                    float al = sop[i] * __expf(-sigma);
                    if (al >= ALPHA_THRESH) {
                        al = fminf(al, ALPHA_CAP);
                        float w = al * T;
                        accr += w * sr[i];
                        accg += w * sg[i];
                        accb += w * sbl[i];
                        T *= (1.0f - al);
                        if (T < TRANS_THRESH) { done = true; break; }
                    }
                }
            }
        }
        // barrier doubles as: (a) all-done vote, (b) protects LDS reuse
        if (__syncthreads_and((int)done)) break;
    }

    const int o = (y * IMG_W + x) * 3;
    out[o]     = accr;
    out[o + 1] = accg;
    out[o + 2] = accb;   // BG = 0, so t_rem term vanishes
}

extern "C" void kernel_launch(void* const* d_in, const int* in_sizes, int n_in,
                              void* d_out, int out_size, void* d_ws, size_t ws_size,
                              hipStream_t stream)
{
    const float* means2d = (const float*)d_in[0];  // (G,2)
    const float* conics  = (const float*)d_in[1];  // (G,3)
    const float* colors  = (const float*)d_in[2];  // (G,3)
    const float* opac    = (const float*)d_in[3];  // (G,)
    const float* depths  = (const float*)d_in[4];  // (G,)
    float* out = (float*)d_out;
    int* order = (int*)d_ws;                       // G ints = 32 KB of ws

    sort_kernel<<<1, SORT_THREADS, 0, stream>>>(depths, order);
    raster_kernel<<<dim3(IMG_W / 16, IMG_H / 16), dim3(16, 16), 0, stream>>>(
        order, means2d, conics, colors, opac, out);
}

// Round 2
// 133.968 us; speedup vs baseline: 13.7374x; 13.7374x over previous
//
#include <hip/hip_runtime.h>

#define G 8192
#define IMG_W 512
#define IMG_H 512
#define TILE 16
#define NTX (IMG_W / TILE)
#define NTY (IMG_H / TILE)
#define BLK 256
#define CAP 1024            // per-tile list capacity (avg ~190, 40-sigma safe)
#define ALPHA_THRESH (1.0f/255.0f)
#define ALPHA_CAP 0.99f
#define TRANS_THRESH 1e-4f

// -----------------------------------------------------------------------
// Kernel 0: per-gaussian conservative AABB of the alpha>=1/255 ellipse.
// alpha = op*exp(-sigma) with sigma>=0 masked; alpha can reach 1/255 only
// where sigma <= smax = ln(255*op). Tight ellipse AABB half-extents are
// sqrt(2*smax*(A^-1)_ii) with A=[[a,b],[b,c]] the conic; (A^-1)_xx=c/det,
// (A^-1)_yy=a/det. Inflate (x1.0001 + 0.01px) to absorb float rounding at
// the boundary -> exclusion is exact w.r.t. the reference's threshold test.
// bbox = (xmin, xmax, ymin, ymax); op*255 < 1 -> empty box (global cull).
// -----------------------------------------------------------------------
__global__ __launch_bounds__(BLK)
void bbox_kernel(const float* __restrict__ means2d,
                 const float* __restrict__ conics,
                 const float* __restrict__ opac,
                 float4* __restrict__ bbox)
{
    int g = blockIdx.x * BLK + threadIdx.x;
    if (g >= G) return;
    float op = opac[g];
    float4 bb;
    if (op * 255.0f < 1.0f) {
        bb = make_float4(1e30f, -1e30f, 1e30f, -1e30f);
    } else {
        float smax = __logf(op * 255.0f);
        float a = conics[3*g], b = conics[3*g+1], c = conics[3*g+2];
        float det = fmaxf(a * c - b * b, 1e-12f);
        float rx = sqrtf(fmaxf(2.0f * smax * c / det, 0.0f)) * 1.0001f + 0.01f;
        float ry = sqrtf(fmaxf(2.0f * smax * a / det, 0.0f)) * 1.0001f + 0.01f;
        float mx = means2d[2*g], my = means2d[2*g+1];
        bb = make_float4(mx - rx, mx + rx, my - ry, my + ry);
    }
    bbox[g] = bb;
}

// -----------------------------------------------------------------------
// Kernel 1 (fused, one block per 16x16 tile):
//  Phase 1: scan all G gaussians in index order, AABB-overlap test against
//           the tile's pixel-center extent, ordered ballot compaction of
//           indices into an LDS list (preserves index order).
//  Phase 2: LDS bitonic sort of the list by key (depth_bits<<13)|idx —
//           depths>0 so float bits are monotone; idx tiebreak reproduces
//           the reference's *stable* argsort restricted to this tile.
//  Phase 3: chunked LDS staging + per-pixel front-to-back compositing
//           (same math as the validated Round-1 kernel), exact early-out
//           at T < 1e-4 via block vote.
// -----------------------------------------------------------------------
__global__ __launch_bounds__(BLK)
void tile_kernel(const float4* __restrict__ bbox,
                 const float*  __restrict__ depths,
                 const float*  __restrict__ means2d,
                 const float*  __restrict__ conics,
                 const float*  __restrict__ colors,
                 const float*  __restrict__ opac,
                 float*        __restrict__ out)
{
    __shared__ unsigned short slist[CAP];
    __shared__ unsigned long long keys[CAP];
    __shared__ int wtot[4];
    __shared__ int scount;
    __shared__ float smx[BLK], smy[BLK], sa[BLK], sb[BLK], sc[BLK];
    __shared__ float sr[BLK], sg[BLK], sbl[BLK], sop[BLK];

    const int tx = threadIdx.x, ty = threadIdx.y;
    const int t = ty * TILE + tx;
    const int lane = t & 63, w = t >> 6;

    // tile pixel-center extent
    const float tx0 = (float)(blockIdx.x * TILE) + 0.5f;
    const float tx1 = tx0 + (float)(TILE - 1);
    const float ty0 = (float)(blockIdx.y * TILE) + 0.5f;
    const float ty1 = ty0 + (float)(TILE - 1);

    if (t == 0) scount = 0;
    __syncthreads();

    // ---- Phase 1: ordered compaction ----
    for (int base = 0; base < G; base += BLK) {
        int g = base + t;
        float4 bb = bbox[g];
        bool hit = (bb.x <= tx1) && (bb.y >= tx0) &&
                   (bb.z <= ty1) && (bb.w >= ty0);
        unsigned long long m = __ballot(hit);
        if (lane == 0) wtot[w] = __popcll(m);
        int pre = __popcll(m & ((1ull << lane) - 1ull));
        __syncthreads();
        if (hit) {
            int offs = scount + pre;
            for (int ww = 0; ww < w; ++ww) offs += wtot[ww];
            if (offs < CAP) slist[offs] = (unsigned short)g;
        }
        __syncthreads();
        if (t == 0) scount += wtot[0] + wtot[1] + wtot[2] + wtot[3];
        __syncthreads();
    }
    int N = min(scount, CAP);

    // ---- Phase 2: stable depth sort of the tile list ----
    int N2 = 1;
    while (N2 < N) N2 <<= 1;          // next pow2 (N2>=1)
    for (int i = t; i < N2; i += BLK) {
        keys[i] = (i < N)
            ? (((unsigned long long)__float_as_uint(depths[slist[i]]) << 13)
               | (unsigned long long)slist[i])
            : 0xffffffffffffffffull;
    }
    __syncthreads();
    for (int k = 2; k <= N2; k <<= 1) {
        for (int j = k >> 1; j > 0; j >>= 1) {
            for (int i = t; i < N2; i += BLK) {
                int ixj = i ^ j;
                if (ixj > i) {
                    unsigned long long va = keys[i], vb = keys[ixj];
                    bool up = ((i & k) == 0);
                    if ((va > vb) == up) { keys[i] = vb; keys[ixj] = va; }
                }
            }
            __syncthreads();
        }
    }
    for (int i = t; i < N; i += BLK)
        slist[i] = (unsigned short)(keys[i] & 0x1fffull);
    __syncthreads();

    // ---- Phase 3: composite ----
    const float px = tx0 + (float)tx;
    const float py = ty0 + (float)ty;
    float T = 1.0f, accr = 0.0f, accg = 0.0f, accb = 0.0f;
    bool done = false;

    for (int base = 0; base < N; base += BLK) {
        int n = min(BLK, N - base);
        if (t < n) {
            int idx = slist[base + t];
            smx[t] = means2d[2*idx];
            smy[t] = means2d[2*idx + 1];
            sa [t] = conics[3*idx];
            sb [t] = conics[3*idx + 1];
            sc [t] = conics[3*idx + 2];
            sr [t] = colors[3*idx];
            sg [t] = colors[3*idx + 1];
            sbl[t] = colors[3*idx + 2];
            sop[t] = opac[idx];
        }
        __syncthreads();
        if (!done) {
            for (int i = 0; i < n; ++i) {
                float dx = px - smx[i];
                float dy = py - smy[i];
                float sigma = 0.5f * (sa[i]*dx*dx + sc[i]*dy*dy) + sb[i]*dx*dy;
                if (sigma >= 0.0f) {
                    float al = sop[i] * __expf(-sigma);
                    if (al >= ALPHA_THRESH) {
                        al = fminf(al, ALPHA_CAP);
                        float wgt = al * T;
                        accr += wgt * sr[i];
                        accg += wgt * sg[i];
                        accb += wgt * sbl[i];
                        T *= (1.0f - al);
                        if (T < TRANS_THRESH) { done = true; break; }
                    }
                }
            }
        }
        if (__syncthreads_and((int)done)) break;
    }

    const int x = blockIdx.x * TILE + tx;
    const int y = blockIdx.y * TILE + ty;
    const int o = (y * IMG_W + x) * 3;
    out[o]     = accr;
    out[o + 1] = accg;
    out[o + 2] = accb;   // BG = 0 -> t_rem term vanishes
}

extern "C" void kernel_launch(void* const* d_in, const int* in_sizes, int n_in,
                              void* d_out, int out_size, void* d_ws, size_t ws_size,
                              hipStream_t stream)
{
    const float* means2d = (const float*)d_in[0];  // (G,2)
    const float* conics  = (const float*)d_in[1];  // (G,3)
    const float* colors  = (const float*)d_in[2];  // (G,3)
    const float* opac    = (const float*)d_in[3];  // (G,)
    const float* depths  = (const float*)d_in[4];  // (G,)
    float* out = (float*)d_out;
    float4* bbox = (float4*)d_ws;                  // G float4 = 131 KB of ws

    bbox_kernel<<<G / BLK, BLK, 0, stream>>>(means2d, conics, opac, bbox);
    tile_kernel<<<dim3(NTX, NTY), dim3(TILE, TILE), 0, stream>>>(
        bbox, depths, means2d, conics, colors, opac, out);
}

// Round 3
// 93.832 us; speedup vs baseline: 19.6134x; 1.4277x over previous
//
#include <hip/hip_runtime.h>

#define G 8192
#define IMG_W 512
#define IMG_H 512
#define TILE 16
#define NTX (IMG_W / TILE)
#define NTY (IMG_H / TILE)
#define BLK 256
#define CAP 1024            // per-tile list capacity (avg ~190)
#define ALPHA_THRESH (1.0f/255.0f)
#define ALPHA_CAP 0.99f
#define TRANS_THRESH 1e-4f

// -----------------------------------------------------------------------
// Kernel 0: per-gaussian tile-span, packed into ONE u32 (txmin,txmax,
// tymin,tymax as bytes). alpha = op*exp(-sigma) >= 1/255 requires
// sigma <= smax = ln(255*op); tight ellipse AABB half-extents are
// sqrt(2*smax*(A^-1)_ii), inflated (x1.0001 + 0.01px) so float rounding
// can never cause a false exclusion -> culling is exact.
// Tile tx covers pixel centers [16tx+0.5, 16tx+15.5]:
//   txmin = ceil((xmin-15.5)/16), txmax = floor((xmax-0.5)/16).
// Culled gaussians encode txmin=0xFF (matches no tile, btx<=31).
// Whole table = 32 KB -> L1-resident during the tile scan.
// -----------------------------------------------------------------------
__global__ __launch_bounds__(BLK)
void range_kernel(const float* __restrict__ means2d,
                  const float* __restrict__ conics,
                  const float* __restrict__ opac,
                  unsigned int* __restrict__ ranges)
{
    int g = blockIdx.x * BLK + threadIdx.x;
    if (g >= G) return;
    float op = opac[g];
    unsigned int packed = 0xFFu;          // default: culled
    if (op * 255.0f >= 1.0f) {
        float smax = __logf(op * 255.0f);
        float a = conics[3*g], b = conics[3*g+1], c = conics[3*g+2];
        float det = fmaxf(a * c - b * b, 1e-12f);
        float rx = sqrtf(fmaxf(2.0f * smax * c / det, 0.0f)) * 1.0001f + 0.01f;
        float ry = sqrtf(fmaxf(2.0f * smax * a / det, 0.0f)) * 1.0001f + 0.01f;
        float mx = means2d[2*g], my = means2d[2*g+1];
        int txmin = (int)ceilf ((mx - rx - 15.5f) * 0.0625f);
        int txmax = (int)floorf((mx + rx -  0.5f) * 0.0625f);
        int tymin = (int)ceilf ((my - ry - 15.5f) * 0.0625f);
        int tymax = (int)floorf((my + ry -  0.5f) * 0.0625f);
        if (!(txmax < 0 || txmin > NTX-1 || tymax < 0 || tymin > NTY-1 ||
              txmin > txmax || tymin > tymax)) {
            txmin = max(txmin, 0); txmax = min(txmax, NTX-1);
            tymin = max(tymin, 0); tymax = min(tymax, NTY-1);
            packed = (unsigned)txmin | ((unsigned)txmax << 8)
                   | ((unsigned)tymin << 16) | ((unsigned)tymax << 24);
        }
    }
    ranges[g] = packed;
}

__device__ __forceinline__ int hitp(unsigned p, unsigned btx, unsigned bty)
{
    return (btx >= (p & 0xffu)) & (btx <= ((p >> 8) & 0xffu)) &
           (bty >= ((p >> 16) & 0xffu)) & (bty <= (p >> 24));
}

// -----------------------------------------------------------------------
// Kernel 1 (one block per 16x16 tile):
//  Phase 1: barrier-free two-pass scan. Each wave owns a contiguous 2048-
//           gaussian range (8 x uint4 loads, kept in registers). Pass A
//           counts hits (shuffle reduce); ONE barrier; pass B ballot-
//           compacts indices into LDS at exact offsets -> list is in
//           ascending gaussian-index order.
//  Phase 2: rank sort by key (depth_bits<<13)|idx: each thread counts
//           smaller keys over lockstep LDS-broadcast reads, scatters.
//           Keys distinct -> permutation. Reproduces the reference's
//           stable argsort restricted to this tile. 2 barriers.
//  Phase 3: chunked LDS staging + branchless front-to-back compositing
//           (math identical to the validated Round-2 kernel), exact
//           early-out at T < 1e-4 via block vote.
// -----------------------------------------------------------------------
__global__ __launch_bounds__(BLK)
void tile_kernel(const unsigned int* __restrict__ ranges,
                 const float* __restrict__ depths,
                 const float* __restrict__ means2d,
                 const float* __restrict__ conics,
                 const float* __restrict__ colors,
                 const float* __restrict__ opac,
                 float*       __restrict__ out)
{
    __shared__ unsigned short slist[CAP];
    __shared__ unsigned long long keys[CAP];
    __shared__ int woff[4];
    __shared__ float smx[BLK], smy[BLK], sa[BLK], sb[BLK], sc[BLK];
    __shared__ float sr[BLK], sg[BLK], sbl[BLK], sop[BLK];

    const int tx = threadIdx.x, ty = threadIdx.y;
    const int t = ty * TILE + tx;
    const int lane = t & 63, w = t >> 6;
    const unsigned btx = blockIdx.x, bty = blockIdx.y;

    // ---- Phase 1, pass A: load + count (no barriers) ----
    const uint4* r4 = (const uint4*)ranges;
    const int wbase = w * (G / 4);            // 2048 gaussians per wave
    uint4 rv[8];
    #pragma unroll
    for (int i = 0; i < 8; ++i)
        rv[i] = r4[(wbase >> 2) + i * 64 + lane];

    int cnt = 0;
    #pragma unroll
    for (int i = 0; i < 8; ++i)
        cnt += hitp(rv[i].x, btx, bty) + hitp(rv[i].y, btx, bty)
             + hitp(rv[i].z, btx, bty) + hitp(rv[i].w, btx, bty);
    #pragma unroll
    for (int d = 1; d < 64; d <<= 1) cnt += __shfl_xor(cnt, d);
    if (lane == 0) woff[w] = cnt;
    __syncthreads();

    int offs = 0;
    for (int ww = 0; ww < w; ++ww) offs += woff[ww];
    const int N = min(woff[0] + woff[1] + woff[2] + woff[3], CAP);

    // ---- Phase 1, pass B: ballot compaction (no barriers in loop) ----
    const unsigned long long lt = (1ull << lane) - 1ull;
    #pragma unroll
    for (int i = 0; i < 8; ++i) {
        int gbase = wbase + i * 256 + lane * 4;
        int h0 = hitp(rv[i].x, btx, bty), h1 = hitp(rv[i].y, btx, bty);
        int h2 = hitp(rv[i].z, btx, bty), h3 = hitp(rv[i].w, btx, bty);
        unsigned long long m0 = __ballot(h0), m1 = __ballot(h1);
        unsigned long long m2 = __ballot(h2), m3 = __ballot(h3);
        int pos = offs + __popcll(m0 & lt) + __popcll(m1 & lt)
                       + __popcll(m2 & lt) + __popcll(m3 & lt);
        if (h0) { if (pos < CAP) slist[pos] = (unsigned short)(gbase    ); pos++; }
        if (h1) { if (pos < CAP) slist[pos] = (unsigned short)(gbase + 1); pos++; }
        if (h2) { if (pos < CAP) slist[pos] = (unsigned short)(gbase + 2); pos++; }
        if (h3) { if (pos < CAP) slist[pos] = (unsigned short)(gbase + 3); pos++; }
        offs += __popcll(m0) + __popcll(m1) + __popcll(m2) + __popcll(m3);
    }
    __syncthreads();

    // ---- Phase 2: rank sort (stable argsort by (depth, idx)) ----
    for (int i = t; i < N; i += BLK) {
        unsigned idx = slist[i];
        keys[i] = ((unsigned long long)__float_as_uint(depths[idx]) << 13)
                | (unsigned long long)idx;
    }
    __syncthreads();
    for (int i = t; i < N; i += BLK) {
        unsigned long long ke = keys[i];
        int r = 0;
        #pragma unroll 4
        for (int j = 0; j < N; ++j) r += (keys[j] < ke);
        slist[r] = (unsigned short)(ke & 0x1fffull);
    }
    __syncthreads();

    // ---- Phase 3: composite ----
    const float px = (float)(blockIdx.x * TILE + tx) + 0.5f;
    const float py = (float)(blockIdx.y * TILE + ty) + 0.5f;
    float T = 1.0f, accr = 0.0f, accg = 0.0f, accb = 0.0f;
    bool done = false;

    for (int base = 0; base < N; base += BLK) {
        int n = min(BLK, N - base);
        if (t < n) {
            int idx = slist[base + t];
            smx[t] = means2d[2*idx];
            smy[t] = means2d[2*idx + 1];
            sa [t] = conics[3*idx];
            sb [t] = conics[3*idx + 1];
            sc [t] = conics[3*idx + 2];
            sr [t] = colors[3*idx];
            sg [t] = colors[3*idx + 1];
            sbl[t] = colors[3*idx + 2];
            sop[t] = opac[idx];
        }
        __syncthreads();
        if (!done) {
            for (int i = 0; i < n; ++i) {
                float dx = px - smx[i];
                float dy = py - smy[i];
                float sigma = 0.5f * (sa[i]*dx*dx + sc[i]*dy*dy) + sb[i]*dx*dy;
                float al = sop[i] * __expf(-sigma);
                bool ok = (sigma >= 0.0f) && (al >= ALPHA_THRESH);
                al = ok ? fminf(al, ALPHA_CAP) : 0.0f;
                float wgt = al * T;
                accr = fmaf(wgt, sr[i],  accr);
                accg = fmaf(wgt, sg[i],  accg);
                accb = fmaf(wgt, sbl[i], accb);
                T *= (1.0f - al);
                if (T < TRANS_THRESH) { done = true; break; }
            }
        }
        if (__syncthreads_and((int)done)) break;
    }

    const int o = ((blockIdx.y * TILE + ty) * IMG_W + blockIdx.x * TILE + tx) * 3;
    out[o]     = accr;
    out[o + 1] = accg;
    out[o + 2] = accb;   // BG = 0 -> t_rem term vanishes
}

extern "C" void kernel_launch(void* const* d_in, const int* in_sizes, int n_in,
                              void* d_out, int out_size, void* d_ws, size_t ws_size,
                              hipStream_t stream)
{
    const float* means2d = (const float*)d_in[0];  // (G,2)
    const float* conics  = (const float*)d_in[1];  // (G,3)
    const float* colors  = (const float*)d_in[2];  // (G,3)
    const float* opac    = (const float*)d_in[3];  // (G,)
    const float* depths  = (const float*)d_in[4];  // (G,)
    float* out = (float*)d_out;
    unsigned int* ranges = (unsigned int*)d_ws;    // G u32 = 32 KB of ws

    range_kernel<<<G / BLK, BLK, 0, stream>>>(means2d, conics, opac, ranges);
    tile_kernel<<<dim3(NTX, NTY), dim3(TILE, TILE), 0, stream>>>(
        ranges, depths, means2d, conics, colors, opac, out);
}

// Round 4
// 89.882 us; speedup vs baseline: 20.4754x; 1.0439x over previous
//
#include <hip/hip_runtime.h>

#define G 8192
#define IMG_W 512
#define IMG_H 512
#define TILE 16
#define NTX (IMG_W / TILE)
#define NTY (IMG_H / TILE)
#define BLK 256
#define CAP 1024            // per-tile list capacity (avg ~190)
#define ALPHA_THRESH (1.0f/255.0f)
#define ALPHA_CAP 0.99f
#define TRANS_THRESH 1e-4f

// -----------------------------------------------------------------------
// Kernel 0: per-gaussian tile-span, packed into ONE u32 (txmin,txmax,
// tymin,tymax as bytes). alpha = op*exp(-sigma) >= 1/255 requires
// sigma <= smax = ln(255*op); tight ellipse AABB half-extents are
// sqrt(2*smax*(A^-1)_ii), inflated (x1.0001 + 0.01px) so float rounding
// can never cause a false exclusion -> culling is exact.
// -----------------------------------------------------------------------
__global__ __launch_bounds__(BLK)
void range_kernel(const float* __restrict__ means2d,
                  const float* __restrict__ conics,
                  const float* __restrict__ opac,
                  unsigned int* __restrict__ ranges)
{
    int g = blockIdx.x * BLK + threadIdx.x;
    if (g >= G) return;
    float op = opac[g];
    unsigned int packed = 0xFFu;          // default: culled
    if (op * 255.0f >= 1.0f) {
        float smax = __logf(op * 255.0f);
        float a = conics[3*g], b = conics[3*g+1], c = conics[3*g+2];
        float det = fmaxf(a * c - b * b, 1e-12f);
        float rx = sqrtf(fmaxf(2.0f * smax * c / det, 0.0f)) * 1.0001f + 0.01f;
        float ry = sqrtf(fmaxf(2.0f * smax * a / det, 0.0f)) * 1.0001f + 0.01f;
        float mx = means2d[2*g], my = means2d[2*g+1];
        int txmin = (int)ceilf ((mx - rx - 15.5f) * 0.0625f);
        int txmax = (int)floorf((mx + rx -  0.5f) * 0.0625f);
        int tymin = (int)ceilf ((my - ry - 15.5f) * 0.0625f);
        int tymax = (int)floorf((my + ry -  0.5f) * 0.0625f);
        if (!(txmax < 0 || txmin > NTX-1 || tymax < 0 || tymin > NTY-1 ||
              txmin > txmax || tymin > tymax)) {
            txmin = max(txmin, 0); txmax = min(txmax, NTX-1);
            tymin = max(tymin, 0); tymax = min(tymax, NTY-1);
            packed = (unsigned)txmin | ((unsigned)txmax << 8)
                   | ((unsigned)tymin << 16) | ((unsigned)tymax << 24);
        }
    }
    ranges[g] = packed;
}

__device__ __forceinline__ int hitp(unsigned p, unsigned btx, unsigned bty)
{
    return (btx >= (p & 0xffu)) & (btx <= ((p >> 8) & 0xffu)) &
           (bty >= ((p >> 16) & 0xffu)) & (bty <= (p >> 24));
}

// -----------------------------------------------------------------------
// Kernel 1 (one block per 16x16 tile):
//  Phase 1: barrier-free two-pass scan (registers hold the 32KB range
//           table slice), ballot compaction in gaussian-index order.
//  Phase 2: rank sort by (depth_bits<<13)|idx — reproduces the stable
//           argsort restricted to this tile.
//  Phase 3: chunked LDS staging as PACKED float4s — 2x ds_read_b128 +
//           1x ds_read_b32 per gaussian instead of 9x ds_read_b32 —
//           strip-mined x4 with the T<1e-4 exit at group boundaries
//           (padded slots are exact zero-gaussians).
// -----------------------------------------------------------------------
__global__ __launch_bounds__(BLK)
void tile_kernel(const unsigned int* __restrict__ ranges,
                 const float* __restrict__ depths,
                 const float* __restrict__ means2d,
                 const float* __restrict__ conics,
                 const float* __restrict__ colors,
                 const float* __restrict__ opac,
                 float*       __restrict__ out)
{
    __shared__ unsigned short slist[CAP];
    __shared__ unsigned long long keys[CAP];
    __shared__ int woff[4];
    __shared__ float4 sq0[BLK];   // mx, my, a, b
    __shared__ float4 sq1[BLK];   // c, op, r, g
    __shared__ float  sq2[BLK];   // blue

    const int tx = threadIdx.x, ty = threadIdx.y;
    const int t = ty * TILE + tx;
    const int lane = t & 63, w = t >> 6;
    const unsigned btx = blockIdx.x, bty = blockIdx.y;

    // ---- Phase 1, pass A: load + count (no barriers) ----
    const uint4* r4 = (const uint4*)ranges;
    const int wbase = w * (G / 4);            // 2048 gaussians per wave
    uint4 rv[8];
    #pragma unroll
    for (int i = 0; i < 8; ++i)
        rv[i] = r4[(wbase >> 2) + i * 64 + lane];

    int cnt = 0;
    #pragma unroll
    for (int i = 0; i < 8; ++i)
        cnt += hitp(rv[i].x, btx, bty) + hitp(rv[i].y, btx, bty)
             + hitp(rv[i].z, btx, bty) + hitp(rv[i].w, btx, bty);
    #pragma unroll
    for (int d = 1; d < 64; d <<= 1) cnt += __shfl_xor(cnt, d);
    if (lane == 0) woff[w] = cnt;
    __syncthreads();

    int offs = 0;
    for (int ww = 0; ww < w; ++ww) offs += woff[ww];
    const int N = min(woff[0] + woff[1] + woff[2] + woff[3], CAP);

    // ---- Phase 1, pass B: ballot compaction ----
    const unsigned long long lt = (1ull << lane) - 1ull;
    #pragma unroll
    for (int i = 0; i < 8; ++i) {
        int gbase = wbase + i * 256 + lane * 4;
        int h0 = hitp(rv[i].x, btx, bty), h1 = hitp(rv[i].y, btx, bty);
        int h2 = hitp(rv[i].z, btx, bty), h3 = hitp(rv[i].w, btx, bty);
        unsigned long long m0 = __ballot(h0), m1 = __ballot(h1);
        unsigned long long m2 = __ballot(h2), m3 = __ballot(h3);
        int pos = offs + __popcll(m0 & lt) + __popcll(m1 & lt)
                       + __popcll(m2 & lt) + __popcll(m3 & lt);
        if (h0) { if (pos < CAP) slist[pos] = (unsigned short)(gbase    ); pos++; }
        if (h1) { if (pos < CAP) slist[pos] = (unsigned short)(gbase + 1); pos++; }
        if (h2) { if (pos < CAP) slist[pos] = (unsigned short)(gbase + 2); pos++; }
        if (h3) { if (pos < CAP) slist[pos] = (unsigned short)(gbase + 3); pos++; }
        offs += __popcll(m0) + __popcll(m1) + __popcll(m2) + __popcll(m3);
    }
    __syncthreads();

    // ---- Phase 2: rank sort (stable argsort by (depth, idx)) ----
    for (int i = t; i < N; i += BLK) {
        unsigned idx = slist[i];
        keys[i] = ((unsigned long long)__float_as_uint(depths[idx]) << 13)
                | (unsigned long long)idx;
    }
    __syncthreads();
    for (int i = t; i < N; i += BLK) {
        unsigned long long ke = keys[i];
        int r = 0;
        #pragma unroll 4
        for (int j = 0; j < N; ++j) r += (keys[j] < ke);
        slist[r] = (unsigned short)(ke & 0x1fffull);
    }
    __syncthreads();

    // ---- Phase 3: composite ----
    const float px = (float)(blockIdx.x * TILE + tx) + 0.5f;
    const float py = (float)(blockIdx.y * TILE + ty) + 0.5f;
    float T = 1.0f, accr = 0.0f, accg = 0.0f, accb = 0.0f;
    bool done = false;

    for (int base = 0; base < N; base += BLK) {
        int n = min(BLK, N - base);
        // stage (packed); slots >= n are zero-gaussians (alpha==0 no-ops)
        float4 v0 = make_float4(0.f, 0.f, 0.f, 0.f);
        float4 v1 = make_float4(0.f, 0.f, 0.f, 0.f);
        float  v2 = 0.f;
        if (t < n) {
            int idx = slist[base + t];
            v0 = make_float4(means2d[2*idx], means2d[2*idx+1],
                             conics[3*idx], conics[3*idx+1]);
            v1 = make_float4(conics[3*idx+2], opac[idx],
                             colors[3*idx], colors[3*idx+1]);
            v2 = colors[3*idx+2];
        }
        sq0[t] = v0; sq1[t] = v1; sq2[t] = v2;
        __syncthreads();

        if (!done) {
            int n4 = (n + 3) & ~3;        // padded slots are no-ops
            for (int i = 0; i < n4 && !done; i += 4) {
                #pragma unroll
                for (int u = 0; u < 4; ++u) {
                    float4 q0 = sq0[i + u];       // ds_read_b128 (broadcast)
                    float4 q1 = sq1[i + u];       // ds_read_b128 (broadcast)
                    float  bl = sq2[i + u];       // ds_read_b32
                    float dx = px - q0.x;
                    float dy = py - q0.y;
                    float sigma = 0.5f * (q0.z*dx*dx + q1.x*dy*dy)
                                + q0.w*dx*dy;
                    float al = q1.y * __expf(-sigma);
                    bool ok = (sigma >= 0.0f) && (al >= ALPHA_THRESH);
                    al = ok ? fminf(al, ALPHA_CAP) : 0.0f;
                    float wgt = al * T;
                    accr = fmaf(wgt, q1.z, accr);
                    accg = fmaf(wgt, q1.w, accg);
                    accb = fmaf(wgt, bl,   accb);
                    T *= (1.0f - al);
                }
                // deferred exit: <=3 extra gaussians, each weighted < 1e-4
                if (T < TRANS_THRESH) done = true;
            }
        }
        if (__syncthreads_and((int)done)) break;
    }

    const int o = ((blockIdx.y * TILE + ty) * IMG_W + blockIdx.x * TILE + tx) * 3;
    out[o]     = accr;
    out[o + 1] = accg;
    out[o + 2] = accb;   // BG = 0 -> t_rem term vanishes
}

extern "C" void kernel_launch(void* const* d_in, const int* in_sizes, int n_in,
                              void* d_out, int out_size, void* d_ws, size_t ws_size,
                              hipStream_t stream)
{
    const float* means2d = (const float*)d_in[0];  // (G,2)
    const float* conics  = (const float*)d_in[1];  // (G,3)
    const float* colors  = (const float*)d_in[2];  // (G,3)
    const float* opac    = (const float*)d_in[3];  // (G,)
    const float* depths  = (const float*)d_in[4];  // (G,)
    float* out = (float*)d_out;
    unsigned int* ranges = (unsigned int*)d_ws;    // G u32 = 32 KB of ws

    range_kernel<<<G / BLK, BLK, 0, stream>>>(means2d, conics, opac, ranges);
    tile_kernel<<<dim3(NTX, NTY), dim3(TILE, TILE), 0, stream>>>(
        ranges, depths, means2d, conics, colors, opac, out);
}